// Round 1
// baseline (736.092 us; speedup 1.0000x reference)
//
#include <hip/hip_runtime.h>
#include <math.h>

// Problem constants (from setup_inputs): B=128,N=8 -> M=1024 rows; D=768; T=512; V=49408
#define M_TOTAL 1024
#define DDIM    768
#define TDIM    512
#define VDIM    49408
#define CH      256          // V-chunk per fused-kernel iteration
#define NCH     193          // 49408 / 256
#define NSPLIT  16           // V splits (low bits of blockIdx -> XCD/L2 chunk sharing)
#define NQT     32           // 1024 / 32 query tiles

typedef __bf16 bf16;
typedef __bf16 bf16x8 __attribute__((ext_vector_type(8)));
typedef float  f32x4  __attribute__((ext_vector_type(4)));

// ---------------- Kernel A: kw = audio@W + b, row-normalize -> kwn (bf16) ----
// 128 blocks x 256 thr, 8 query rows per block. fp32 throughout, round at store.
__global__ __launch_bounds__(256) void k_proj(const float* __restrict__ audio,
        const float* __restrict__ W, const float* __restrict__ bias,
        bf16* __restrict__ kwn) {
    __shared__ float a_lds[8 * 768];
    __shared__ float kw_lds[8 * 512];
    __shared__ float rn_lds[8];
    const int tid = threadIdx.x;
    const int q0 = blockIdx.x * 8;

    const float4* asrc = (const float4*)(audio + q0 * 768);
    float4* adst = (float4*)a_lds;
    #pragma unroll
    for (int i = 0; i < 6; ++i) adst[i * 256 + tid] = asrc[i * 256 + tid];
    __syncthreads();

    float acc0[8], acc1[8];
    #pragma unroll
    for (int q = 0; q < 8; ++q) { acc0[q] = 0.f; acc1[q] = 0.f; }
    for (int d = 0; d < 768; ++d) {
        const float w0 = W[d * 512 + tid];
        const float w1 = W[d * 512 + 256 + tid];
        #pragma unroll
        for (int q = 0; q < 8; ++q) {
            const float a = a_lds[q * 768 + d];   // broadcast, conflict-free
            acc0[q] = fmaf(a, w0, acc0[q]);
            acc1[q] = fmaf(a, w1, acc1[q]);
        }
    }
    const float b0 = bias[tid], b1 = bias[256 + tid];
    #pragma unroll
    for (int q = 0; q < 8; ++q) {
        kw_lds[q * 512 + tid]       = acc0[q] + b0;
        kw_lds[q * 512 + 256 + tid] = acc1[q] + b1;
    }
    __syncthreads();

    const int w = tid >> 6, lane = tid & 63;
    for (int qq = 0; qq < 2; ++qq) {
        const int q = w + qq * 4;
        float ss = 0.f;
        #pragma unroll
        for (int i = 0; i < 8; ++i) { const float x = kw_lds[q * 512 + lane + i * 64]; ss = fmaf(x, x, ss); }
        #pragma unroll
        for (int o = 1; o < 64; o <<= 1) ss += __shfl_xor(ss, o);
        if (lane == 0) rn_lds[q] = 1.0f / fmaxf(sqrtf(ss), 1e-8f);
    }
    __syncthreads();
    #pragma unroll
    for (int i = 0; i < 16; ++i) {
        const int idx = i * 256 + tid;
        const int q = idx >> 9;
        kwn[(q0 + q) * 512 + (idx & 511)] = (bf16)(kw_lds[idx] * rn_lds[q]);
    }
}

// ---------------- Kernel B1: emb -> bf16 row-major + rs[v] = 10/max(||e||,eps)
// wave per row; fully coalesced.
__global__ __launch_bounds__(256) void k_embprep(const float* __restrict__ emb,
        bf16* __restrict__ embb, float* __restrict__ rs) {
    const int w = threadIdx.x >> 6, lane = threadIdx.x & 63;
    const int v = blockIdx.x * 4 + w;
    const float4* src = (const float4*)(emb + (size_t)v * 512);
    const float4 x0 = src[lane * 2], x1 = src[lane * 2 + 1];
    float ss = x0.x * x0.x + x0.y * x0.y + x0.z * x0.z + x0.w * x0.w
             + x1.x * x1.x + x1.y * x1.y + x1.z * x1.z + x1.w * x1.w;
    #pragma unroll
    for (int o = 1; o < 64; o <<= 1) ss += __shfl_xor(ss, o);
    if (lane == 0) rs[v] = 10.0f / fmaxf(sqrtf(ss), 1e-8f);  // folds 1/TEMP
    bf16x8 outv;
    outv[0] = (bf16)x0.x; outv[1] = (bf16)x0.y; outv[2] = (bf16)x0.z; outv[3] = (bf16)x0.w;
    outv[4] = (bf16)x1.x; outv[5] = (bf16)x1.y; outv[6] = (bf16)x1.z; outv[7] = (bf16)x1.w;
    *(bf16x8*)(embb + (size_t)v * 512 + lane * 8) = outv;
}

// ---------------- Kernel B2: chunk-tiled transpose embb -> embT --------------
// embT layout: chunk c in [0,193): [t 0..511][vloc 0..255] contiguous (256KB tiles).
// One block per 128-row half-chunk; 133KB LDS tile (gfx950 has 160KB/WG).
#define TPITCH 520
__global__ __launch_bounds__(256) void k_transpose(const bf16* __restrict__ embb,
        bf16* __restrict__ embT) {
    __shared__ unsigned short tile[128 * TPITCH];
    const int tid = threadIdx.x;
    const int h = blockIdx.x;          // half-chunk: 128 rows
    const int v0 = h * 128;
    const uint4* src = (const uint4*)(embb + (size_t)v0 * 512);
    #pragma unroll
    for (int i = 0; i < 32; ++i) {
        const int L = (i * 256 + tid) * 8;         // element in 128x512
        const int v = L >> 9, t = L & 511;
        const uint4 d = src[i * 256 + tid];
        *(uint4*)&tile[v * TPITCH + t] = d;
    }
    __syncthreads();
    const int c = h >> 1, hh = h & 1;
    unsigned short* dst = (unsigned short*)embT + (size_t)c * 131072 + hh * 128;
    #pragma unroll
    for (int i = 0; i < 32; ++i) {
        const int O = (i * 256 + tid) * 8;         // element in 512x128 output
        const int vvk = O & 127, t = O >> 7;
        unsigned short e[8];
        #pragma unroll
        for (int j = 0; j < 8; ++j) e[j] = tile[(vvk + j) * TPITCH + t];
        uint4 o;
        o.x = (unsigned)e[0] | ((unsigned)e[1] << 16);
        o.y = (unsigned)e[2] | ((unsigned)e[3] << 16);
        o.z = (unsigned)e[4] | ((unsigned)e[5] << 16);
        o.w = (unsigned)e[6] | ((unsigned)e[7] << 16);
        *(uint4*)&dst[(size_t)t * 256 + vvk] = o;
    }
}

// ---------------- Kernel C: fused scores -> exp -> P@E accumulate ------------
// Grid 512 = 32 q-tiles x 16 v-splits (split in LOW bits: co-XCD WGs stream the
// same chunks -> L2 reuse). WG = 4 waves; wave wv owns v-slice 64 of each
// 256-chunk for S, and T-slice 128 for PV. No online softmax (logits in
// [-10,10]); partials combined by fp32 atomicAdd into Oacc/Lsum.
__global__ __launch_bounds__(256, 2) void k_attn(const bf16* __restrict__ kwn,
        const bf16* __restrict__ embb, const bf16* __restrict__ embT,
        const float* __restrict__ rs, float* __restrict__ Oacc,
        float* __restrict__ Lsum) {
    __shared__ unsigned short Qlds[32 * 520];   // 32 q-rows, padded pitch
    __shared__ unsigned short Plds[16 * 512];   // P in A-frag-major layout, 16KB
    const int tid = threadIdx.x;
    const int s = blockIdx.x & 15, qt = blockIdx.x >> 4;
    const int q0 = qt * 32;
    const int wv = tid >> 6, lane = tid & 63, lm = lane & 15, lg = lane >> 4;

    {   // stage Q tile (32x512 bf16)
        const uint4* src = (const uint4*)(kwn + q0 * 512);
        #pragma unroll
        for (int i = 0; i < 8; ++i) {
            const int L = (i * 256 + tid) * 8;
            *(uint4*)&Qlds[(L >> 9) * 520 + (L & 511)] = src[i * 256 + tid];
        }
    }
    __syncthreads();

    const f32x4 zero4 = {0.f, 0.f, 0.f, 0.f};
    f32x4 acc[2][8];                       // O: [mb 16q][nb 16t] over T-slice 128
    #pragma unroll
    for (int a = 0; a < 2; ++a)
        #pragma unroll
        for (int b = 0; b < 8; ++b) acc[a][b] = zero4;
    float lacc[2][4] = {{0.f,0.f,0.f,0.f},{0.f,0.f,0.f,0.f}};

    const int c0 = (s * NCH) / NSPLIT, c1 = ((s + 1) * NCH) / NSPLIT;
    for (int c = c0; c < c1; ++c) {
        // ---- S = Qn @ En^T (per wave: 32q x 64v, K=512) ----
        f32x4 sacc[2][4];
        #pragma unroll
        for (int a = 0; a < 2; ++a)
            #pragma unroll
            for (int b = 0; b < 4; ++b) sacc[a][b] = zero4;
        const bf16* Eb = embb + ((size_t)c * 256 + wv * 64) * 512;
        #pragma unroll
        for (int kf = 0; kf < 16; ++kf) {
            const bf16x8 aq0 = *(const bf16x8*)&Qlds[lm * 520 + kf * 32 + lg * 8];
            const bf16x8 aq1 = *(const bf16x8*)&Qlds[(16 + lm) * 520 + kf * 32 + lg * 8];
            #pragma unroll
            for (int nb = 0; nb < 4; ++nb) {
                const bf16x8 bfr = *(const bf16x8*)(Eb + (nb * 16 + lm) * 512 + kf * 32 + lg * 8);
                sacc[0][nb] = __builtin_amdgcn_mfma_f32_16x16x32_bf16(aq0, bfr, sacc[0][nb], 0, 0, 0);
                sacc[1][nb] = __builtin_amdgcn_mfma_f32_16x16x32_bf16(aq1, bfr, sacc[1][nb], 0, 0, 0);
            }
        }
        // ---- p = exp(s * rs[v]); scatter into Plds in A-frag layout ----
        #pragma unroll
        for (int nb = 0; nb < 4; ++nb) {
            const float rsv = rs[c * 256 + wv * 64 + nb * 16 + lm];
            const int kfg = 2 * wv + (nb >> 1);
            const int hi = 2 * (nb & 1) + (lm >> 3);
            const int jj = lm & 7;
            #pragma unroll
            for (int mb = 0; mb < 2; ++mb) {
                const int fragbase = (mb * 8 + kfg) * 512;
                #pragma unroll
                for (int r = 0; r < 4; ++r) {
                    const float p = __expf(sacc[mb][nb][r] * rsv);
                    const bf16 pb = (bf16)p;
                    lacc[mb][r] += (float)pb;   // use rounded value for consistency
                    const int ldest = (lg * 4 + r) + 16 * hi;
                    Plds[fragbase + ldest * 8 + jj] = __builtin_bit_cast(unsigned short, pb);
                }
            }
        }
        __syncthreads();                        // P fully written
        bf16x8 pf[2][8];
        #pragma unroll
        for (int mb = 0; mb < 2; ++mb)
            #pragma unroll
            for (int kf = 0; kf < 8; ++kf)
                pf[mb][kf] = *(const bf16x8*)&Plds[(mb * 8 + kf) * 512 + lane * 8];
        __syncthreads();                        // everyone loaded P; reuse next iter
        // ---- O += P @ E (per wave: 32q x 128t, K=256) ----
        const bf16* ETb = embT + (size_t)c * 131072 + (wv * 128) * 256;
        #pragma unroll
        for (int nb = 0; nb < 8; ++nb) {
            #pragma unroll
            for (int kf = 0; kf < 8; ++kf) {
                const bf16x8 bfr = *(const bf16x8*)(ETb + (nb * 16 + lm) * 256 + kf * 32 + lg * 8);
                acc[0][nb] = __builtin_amdgcn_mfma_f32_16x16x32_bf16(pf[0][kf], bfr, acc[0][nb], 0, 0, 0);
                acc[1][nb] = __builtin_amdgcn_mfma_f32_16x16x32_bf16(pf[1][kf], bfr, acc[1][nb], 0, 0, 0);
            }
        }
    }

    // ---- combine partials across v-splits ----
    #pragma unroll
    for (int mb = 0; mb < 2; ++mb)
        #pragma unroll
        for (int nb = 0; nb < 8; ++nb)
            #pragma unroll
            for (int r = 0; r < 4; ++r) {
                const int q = q0 + mb * 16 + lg * 4 + r;
                const int t = wv * 128 + nb * 16 + lm;
                atomicAdd(&Oacc[q * 512 + t], acc[mb][nb][r]);
            }
    #pragma unroll
    for (int mb = 0; mb < 2; ++mb)
        #pragma unroll
        for (int r = 0; r < 4; ++r) {
            float sum = lacc[mb][r];
            sum += __shfl_xor(sum, 1);
            sum += __shfl_xor(sum, 2);
            sum += __shfl_xor(sum, 4);
            sum += __shfl_xor(sum, 8);
            if (lm == 0) atomicAdd(&Lsum[q0 + mb * 16 + lg * 4 + r], sum);
        }
}

// ---------------- Kernel D: out = Oacc / Lsum --------------------------------
__global__ __launch_bounds__(256) void k_final(const float* __restrict__ Oacc,
        const float* __restrict__ Lsum, float* __restrict__ out) {
    const int i = blockIdx.x * 256 + threadIdx.x;   // float4 index, 131072 total
    const float4 o = ((const float4*)Oacc)[i];
    const float inv = 1.0f / Lsum[i >> 7];          // 128 float4 per row
    float4 r;
    r.x = o.x * inv; r.y = o.y * inv; r.z = o.z * inv; r.w = o.w * inv;
    ((float4*)out)[i] = r;
}

// ---------------- launcher ---------------------------------------------------
// ws layout (bytes):
//   0        kwn   bf16 [1024*512]          1,048,576
//   1048576  rs    f32  [49408]               197,632
//   1246208  Oacc  f32  [1024*512]          2,097,152   (zeroed each launch)
//   3343360  Lsum  f32  [1024]                   4,096   (zeroed each launch)
//   3347456  embb  bf16 [49408*512]        50,593,792
//   53941248 embT  bf16 [49408*512 tiled]  50,593,792
//   total 104,535,040 B
extern "C" void kernel_launch(void* const* d_in, const int* in_sizes, int n_in,
                              void* d_out, int out_size, void* d_ws, size_t ws_size,
                              hipStream_t stream) {
    const float* audio = (const float*)d_in[0];
    const float* W     = (const float*)d_in[1];
    const float* bias  = (const float*)d_in[2];
    const float* emb   = (const float*)d_in[3];
    float* out = (float*)d_out;
    char* ws = (char*)d_ws;

    bf16*  kwn  = (bf16*)(ws);
    float* rs   = (float*)(ws + 1048576);
    float* Oacc = (float*)(ws + 1246208);
    float* Lsum = (float*)(ws + 3343360);
    bf16*  embb = (bf16*)(ws + 3347456);
    bf16*  embT = (bf16*)(ws + 53941248);

    hipMemsetAsync(ws + 1246208, 0, 2097152 + 4096, stream);   // Oacc + Lsum
    k_proj<<<128, 256, 0, stream>>>(audio, W, bias, kwn);
    k_embprep<<<VDIM / 4, 256, 0, stream>>>(emb, embb, rs);
    k_transpose<<<VDIM / 128, 256, 0, stream>>>(embb, embT);
    k_attn<<<NQT * NSPLIT, 256, 0, stream>>>(kwn, embb, embT, rs, Oacc, Lsum);
    k_final<<<(out_size / 4) / 256, 256, 0, stream>>>(Oacc, Lsum, out);
}